// Round 4
// baseline (347.899 us; speedup 1.0000x reference)
//
#include <hip/hip_runtime.h>
#include <stdint.h>

#define NEG_SLOPE 0.01f
#define CHUNK 4096

typedef float f32x4 __attribute__((ext_vector_type(4)));
typedef short short8 __attribute__((ext_vector_type(8)));

__device__ inline short f2bf(float f) {
    union { float f; uint32_t u; } x; x.f = f;
    uint32_t r = x.u + 0x7FFF + ((x.u >> 16) & 1);   // RNE
    return (short)(r >> 16);
}
__device__ inline float bf2f(unsigned short u) {
    union { uint32_t u; float f; } x; x.u = ((uint32_t)u) << 16; return x.f;
}

// ---------------- K_init_bf: counter init + ego fp32 -> bf16 ----------------
__global__ void __launch_bounds__(256) k_init_bf(
        const float* __restrict__ ego, unsigned short* __restrict__ ego_bf,
        int NE8, int* head_cnt, int* head_cur, int* type_cnt, int N) {
    int i = blockIdx.x * 256 + threadIdx.x;
    if (i < N) { head_cnt[i] = 0; head_cur[i] = 0; }
    if (i < 16) type_cnt[i] = 0;
    if (i >= NE8) return;
    const float4* p = (const float4*)ego + (size_t)i * 2;
    float4 a = p[0], b = p[1];
    short8 v;
    v[0] = f2bf(a.x); v[1] = f2bf(a.y); v[2] = f2bf(a.z); v[3] = f2bf(a.w);
    v[4] = f2bf(b.x); v[5] = f2bf(b.y); v[6] = f2bf(b.z); v[7] = f2bf(b.w);
    *(short8*)(ego_bf + (size_t)i * 8) = v;
}

// ---------------- K_w: pack W^T as MFMA A-fragments (bf16) ----------------
// A[m = t4*16 + (lane&15)][k = kh*32 + (lane>>4)*8 + j] = W[r][k][m]
__global__ void __launch_bounds__(512) k_w(const float* __restrict__ rw,
                                           short* __restrict__ wfrag) {
    int r = blockIdx.x;
    int tid = threadIdx.x;
    int lane = tid & 63, pair = tid >> 6;
    int t4 = pair >> 1, kh = pair & 1;
    int c = lane & 15, q = lane >> 4;
    int m = t4 * 16 + c;
    short8 f;
    for (int j = 0; j < 8; ++j) {
        int k = kh * 32 + q * 8 + j;
        f[j] = f2bf(rw[r * 4096 + k * 64 + m]);
    }
    *(short8*)(wfrag + ((size_t)((r * 4 + t4) * 2 + kh) * 64 + lane) * 8) = f;
}

// ---------------- K1: histograms ----------------
__global__ void __launch_bounds__(256) k1_hist(
        const int* __restrict__ head, const int* __restrict__ etype, int E,
        int* head_cnt, int* type_cnt) {
    __shared__ int lcnt[16];
    int t = threadIdx.x;
    if (t < 16) lcnt[t] = 0;
    __syncthreads();
    long long base = (long long)blockIdx.x * CHUNK;
    for (int i = t; i < CHUNK; i += 256) {
        long long e = base + i;
        if (e < E) {
            atomicAdd(&head_cnt[head[e]], 1);
            atomicAdd(&lcnt[etype[e]], 1);
        }
    }
    __syncthreads();
    if (t < 16 && lcnt[t]) atomicAdd(&type_cnt[t], lcnt[t]);
}

// ---------------- K2a: per-block partial sums of head_cnt ----------------
__global__ void __launch_bounds__(512) k2a(const int* __restrict__ head_cnt,
                                           int N, int* partial) {
    __shared__ int sw[8];
    int i = blockIdx.x * 512 + threadIdx.x;
    int v = (i < N) ? head_cnt[i] : 0;
    for (int off = 32; off; off >>= 1) v += __shfl_down(v, off);
    int w = threadIdx.x >> 6, lane = threadIdx.x & 63;
    if (lane == 0) sw[w] = v;
    __syncthreads();
    if (threadIdx.x == 0) {
        int s = 0;
        for (int j = 0; j < 8; ++j) s += sw[j];
        partial[blockIdx.x] = s;
    }
}

// ---------------- K2c: scan -> head_off; block 0 wave 7 does type scan ------
__global__ void __launch_bounds__(512) k2c(const int* __restrict__ head_cnt,
                                           int N, const int* __restrict__ partial,
                                           int* head_off, int E,
                                           const int* __restrict__ type_cnt,
                                           int* type_off_pad, int* type_fill,
                                           int* perm_type) {
    __shared__ int s[512];
    __shared__ int bo_s;
    int t = threadIdx.x;
    if (t < 64) {
        int acc = 0;
        for (int i = t; i < blockIdx.x; i += 64) acc += partial[i];
        for (int off = 32; off; off >>= 1) acc += __shfl_down(acc, off);
        if (t == 0) bo_s = acc;
    }
    int i = blockIdx.x * 512 + t;
    int v = (i < N) ? head_cnt[i] : 0;
    s[t] = v;
    __syncthreads();
    for (int off = 1; off < 512; off <<= 1) {
        int x = (t >= off) ? s[t - off] : 0;
        __syncthreads();
        s[t] += x;
        __syncthreads();
    }
    if (i < N) head_off[i] = s[t] - v + bo_s;
    if (i == 0) head_off[N] = E;
    // type-bucket scan + pad-slot fill (shuffle-only, one wave)
    if (blockIdx.x == 0 && t >= 448) {
        int lane = t & 63;
        int tv = (lane < 16) ? type_cnt[lane] : 0;
        int tp = (tv + 15) & ~15;
        int inc = tp;
        for (int off = 1; off < 16; off <<= 1) {
            int u = __shfl_up(inc, off);
            if (lane >= off) inc += u;
        }
        int excl = inc - tp;
        if (lane < 16) {
            type_off_pad[lane] = excl;
            type_fill[lane] = excl;
            if (lane == 15) type_off_pad[16] = inc;
        }
        for (int r = 0; r < 16; ++r) {
            int b = __shfl(excl, r) + __shfl(tv, r);
            int top1 = (r < 15) ? __shfl(excl, r + 1) : __shfl(inc, 15);
            int pads = top1 - b;
            if (lane < pads) perm_type[b + lane] = -1;
        }
    }
}

// ---------------- K3: type scatter + headpos + group_rel --------------------
__global__ void __launch_bounds__(256) k3_scatter(
        const int* __restrict__ etype, const int* __restrict__ head, int E,
        const int* __restrict__ head_off, int* head_cur,
        int* type_fill, int* perm_type, int* __restrict__ headpos,
        const int* __restrict__ type_off_pad, int* __restrict__ group_rel) {
    __shared__ int lcnt[16], lbase[16], lcur[16], top_s[17];
    int t = threadIdx.x;
    if (t < 16) { lcnt[t] = 0; lcur[t] = 0; }
    if (t < 17) top_s[t] = type_off_pad[t];
    __syncthreads();
    long long base = (long long)blockIdx.x * CHUNK;
    for (int i = t; i < CHUNK; i += 256) {
        long long e = base + i;
        if (e < E) atomicAdd(&lcnt[etype[e]], 1);
    }
    __syncthreads();
    if (t < 16) lbase[t] = atomicAdd(&type_fill[t], lcnt[t]);
    __syncthreads();
    for (int i = t; i < CHUNK; i += 256) {
        long long e = base + i;
        if (e < E) {
            int ty = etype[e];
            int rk = atomicAdd(&lcur[ty], 1);
            perm_type[lbase[ty] + rk] = (int)e;
            int h = head[e];
            headpos[e] = head_off[h] + atomicAdd(&head_cur[h], 1);  // coalesced write
        }
    }
    // group_rel fill (grid-stride; type_off_pad written by k2c)
    int total = top_s[16] >> 4;
    int nthreads = gridDim.x * 256;
    for (int g = blockIdx.x * 256 + t; g < total; g += nthreads) {
        int spos = g << 4;
        int r = 0;
        while (r < 15 && spos >= top_s[r + 1]) ++r;
        group_rel[g] = r;
    }
}

// ---------------- K4: scores via MFMA, pipelined, atomic-free epilogue ------
// D = W^T(A-frag) x HeadRows(B-frag): D col (lane&15) = edge slot,
// D row (q*4+i, tiled by t4) = output column. Epilogue: one 8B int2 store
// {exp_bits, tail} at the precomputed head-sorted position.
__global__ void __launch_bounds__(256) k4_scores(
        const unsigned short* __restrict__ ego_bf, const short* __restrict__ wfrag,
        const int* __restrict__ head, const int* __restrict__ tail,
        const int* __restrict__ perm_type, const int* __restrict__ group_rel,
        const int* __restrict__ type_off_pad, const int* __restrict__ headpos,
        int2* __restrict__ wt_sorted, int n_waves) {
    int wave = (blockIdx.x * blockDim.x + threadIdx.x) >> 6;
    int lane = threadIdx.x & 63;
    int c = lane & 15, q = lane >> 4;
    int G = type_off_pad[16] >> 4;
    int per = (G + n_waves - 1) / n_waves;
    int g0 = wave * per, g1 = min(G, g0 + per);
    if (g0 >= g1) return;
    const short8 z8 = {0, 0, 0, 0, 0, 0, 0, 0};

    // index pipeline, 2 deep (A = group g, B = group g+1)
    int eA = perm_type[(g0 << 4) + c];
    int hA = eA >= 0 ? head[eA] : 0;
    int tA = eA >= 0 ? tail[eA] : 0;
    int pA = eA >= 0 ? headpos[eA] : 0;
    int rA = group_rel[g0];
    int eB = -1, hB = 0, tB = 0, pB = 0, rB = rA;
    if (g0 + 1 < g1) {
        eB = perm_type[((g0 + 1) << 4) + c];
        hB = eB >= 0 ? head[eB] : 0;
        tB = eB >= 0 ? tail[eB] : 0;
        pB = eB >= 0 ? headpos[eB] : 0;
        rB = group_rel[g0 + 1];
    }
    // row data for group g0
    const unsigned short* hr = ego_bf + (size_t)hA * 64;
    short8 b0c = *(const short8*)(hr + q * 8);
    short8 b1c = *(const short8*)(hr + 32 + q * 8);
    const unsigned short* tr = ego_bf + (size_t)tA * 64 + q * 4;
    ushort4 t0c = *(const ushort4*)(tr);
    ushort4 t1c = *(const ushort4*)(tr + 16);
    ushort4 t2c = *(const ushort4*)(tr + 32);
    ushort4 t3c = *(const ushort4*)(tr + 48);

    int cur_r = -1;
    short8 wf[4][2];
    for (int g = g0; g < g1; ++g) {
        // prefetch rows for g+1 (B indices already resident)
        const unsigned short* hrn = ego_bf + (size_t)hB * 64;
        short8 b0n = *(const short8*)(hrn + q * 8);
        short8 b1n = *(const short8*)(hrn + 32 + q * 8);
        const unsigned short* trn = ego_bf + (size_t)tB * 64 + q * 4;
        ushort4 t0n = *(const ushort4*)(trn);
        ushort4 t1n = *(const ushort4*)(trn + 16);
        ushort4 t2n = *(const ushort4*)(trn + 32);
        ushort4 t3n = *(const ushort4*)(trn + 48);
        // prefetch indices for g+2
        int eN = -1, hN = 0, tN = 0, pN = 0, rN = rB;
        if (g + 2 < g1) {
            eN = perm_type[((g + 2) << 4) + c];
            hN = eN >= 0 ? head[eN] : 0;
            tN = eN >= 0 ? tail[eN] : 0;
            pN = eN >= 0 ? headpos[eN] : 0;
            rN = group_rel[g + 2];
        }
        if (rA != cur_r) {                       // wave-uniform, rare
            cur_r = rA;
            const short* wp = wfrag + (size_t)rA * 4096;
            for (int t4 = 0; t4 < 4; ++t4)
                for (int kh = 0; kh < 2; ++kh)
                    wf[t4][kh] = *(const short8*)(wp + ((t4 * 2 + kh) * 64 + lane) * 8);
        }
        short8 bb0 = b0c, bb1 = b1c;
        if (eA < 0) { bb0 = z8; bb1 = z8; }
        f32x4 acc[4];
        for (int t4 = 0; t4 < 4; ++t4) {
            f32x4 a = {0.f, 0.f, 0.f, 0.f};
            a = __builtin_amdgcn_mfma_f32_16x16x32_bf16(wf[t4][0], bb0, a, 0, 0, 0);
            a = __builtin_amdgcn_mfma_f32_16x16x32_bf16(wf[t4][1], bb1, a, 0, 0, 0);
            acc[t4] = a;
        }
        float d = acc[0][0] * bf2f(t0c.x) + acc[0][1] * bf2f(t0c.y)
                + acc[0][2] * bf2f(t0c.z) + acc[0][3] * bf2f(t0c.w)
                + acc[1][0] * bf2f(t1c.x) + acc[1][1] * bf2f(t1c.y)
                + acc[1][2] * bf2f(t1c.z) + acc[1][3] * bf2f(t1c.w)
                + acc[2][0] * bf2f(t2c.x) + acc[2][1] * bf2f(t2c.y)
                + acc[2][2] * bf2f(t2c.z) + acc[2][3] * bf2f(t2c.w)
                + acc[3][0] * bf2f(t3c.x) + acc[3][1] * bf2f(t3c.y)
                + acc[3][2] * bf2f(t3c.z) + acc[3][3] * bf2f(t3c.w);
        d += __shfl_xor(d, 16);
        d += __shfl_xor(d, 32);
        if (q == 0 && eA >= 0) {
            float sc = d > 0.f ? d : NEG_SLOPE * d;
            int2 v;
            v.x = __float_as_int(__expf(sc));
            v.y = tA;
            wt_sorted[pA] = v;                   // plain 8B scatter, no atomic
        }
        // rotate pipeline
        eA = eB; hA = hB; tA = tB; pA = pB; rA = rB;
        eB = eN; hB = hN; tB = tN; pB = pN; rB = rN;
        b0c = b0n; b1c = b1n;
        t0c = t0n; t1c = t1n; t2c = t2n; t3c = t3n;
    }
}

// ---------------- K5: per-head aggregation, batched gathers -----------------
__global__ void __launch_bounds__(256) k5_agg(
        const unsigned short* __restrict__ ego_bf,
        const int2* __restrict__ wt_sorted,
        const int* __restrict__ head_off, float* __restrict__ out, int N) {
    int wave = (blockIdx.x * blockDim.x + threadIdx.x) >> 6;
    int lane = threadIdx.x & 63;
    if (wave >= N) return;
    int g8 = lane >> 3, c8 = lane & 7;   // g8 = edge slot, c8 -> cols 8c8..8c8+7
    int s0 = head_off[wave], s1 = head_off[wave + 1];
    int cnt = s1 - s0;
    float a0 = 0.f, a1 = 0.f, a2 = 0.f, a3 = 0.f;
    float a4 = 0.f, a5 = 0.f, a6 = 0.f, a7 = 0.f, den = 0.f;
    for (int base = s0; base < s1; base += 64) {
        int idx = base + lane;
        int tnL = 0; float wL = 0.f;
        if (idx < s1) {
            int2 p = wt_sorted[idx];             // coalesced
            wL = __int_as_float(p.x);
            tnL = p.y;
        }
        int ng = min(64, s1 - base);
        short8 rows[8];
        float ws[8];
        #pragma unroll
        for (int s = 0; s < 8; ++s) {            // issue all gathers up front
            int j = s * 8 + g8;
            int tn = __shfl(tnL, j);
            ws[s] = __shfl(wL, j);
            if (s * 8 < ng)                       // wave-uniform guard
                rows[s] = *(const short8*)(ego_bf + (size_t)tn * 64 + c8 * 8);
        }
        #pragma unroll
        for (int s = 0; s < 8; ++s) {
            if (s * 8 < ng) {
                float we = ws[s];
                den += we;
                a0 += we * bf2f((unsigned short)rows[s][0]);
                a1 += we * bf2f((unsigned short)rows[s][1]);
                a2 += we * bf2f((unsigned short)rows[s][2]);
                a3 += we * bf2f((unsigned short)rows[s][3]);
                a4 += we * bf2f((unsigned short)rows[s][4]);
                a5 += we * bf2f((unsigned short)rows[s][5]);
                a6 += we * bf2f((unsigned short)rows[s][6]);
                a7 += we * bf2f((unsigned short)rows[s][7]);
            }
        }
    }
    for (int off = 8; off < 64; off <<= 1) {      // sum over g8, keep c8
        den += __shfl_xor(den, off);
        a0 += __shfl_xor(a0, off); a1 += __shfl_xor(a1, off);
        a2 += __shfl_xor(a2, off); a3 += __shfl_xor(a3, off);
        a4 += __shfl_xor(a4, off); a5 += __shfl_xor(a5, off);
        a6 += __shfl_xor(a6, off); a7 += __shfl_xor(a7, off);
    }
    if (lane < 8) {
        float sc = (cnt > 0) ? 1.f / (den * (float)cnt) : 0.f;
        float4 v0 = {a0 * sc, a1 * sc, a2 * sc, a3 * sc};
        float4 v1 = {a4 * sc, a5 * sc, a6 * sc, a7 * sc};
        float* op = out + (size_t)wave * 64 + c8 * 8;
        *(float4*)op = v0;
        *(float4*)(op + 4) = v1;
    }
}

extern "C" void kernel_launch(void* const* d_in, const int* in_sizes, int n_in,
                              void* d_out, int out_size, void* d_ws, size_t ws_size,
                              hipStream_t stream) {
    const float* ego = (const float*)d_in[0];
    const float* rw  = (const float*)d_in[1];
    const int* eidx  = (const int*)d_in[2];
    const int* etyp  = (const int*)d_in[3];
    int N = in_sizes[0] / 64;
    int E = in_sizes[3];
    const int* head = eidx;
    const int* tail = eidx + E;
    float* out = (float*)d_out;

    char* ws = (char*)d_ws;
    size_t o = 0;
    auto take = [&](size_t bytes) -> char* {
        char* p = ws + o;
        o = (o + bytes + 255) & ~(size_t)255;
        return p;
    };
    int PT   = E + 256;
    int Gmax = (E + 255) / 16 + 16;
    int nb2  = (N + 511) / 512;
    unsigned short* ego_bf = (unsigned short*)take((size_t)N * 64 * 2);
    short* wfrag      = (short*)take(16 * 4096 * 2);
    int2* wt_sorted   = (int2*)take((size_t)E * 8);
    int* perm_type    = (int*)take((size_t)PT * 4);
    int* headpos      = (int*)take((size_t)E * 4);
    int* head_cnt     = (int*)take((size_t)N * 4);
    int* head_off     = (int*)take((size_t)(N + 1) * 4);
    int* head_cur     = (int*)take((size_t)N * 4);
    int* type_cnt     = (int*)take(64);
    int* type_off_pad = (int*)take(68);
    int* type_fill    = (int*)take(64);
    int* group_rel    = (int*)take((size_t)Gmax * 4);
    int* partial      = (int*)take((size_t)nb2 * 4);
    (void)ws_size; (void)n_in; (void)out_size;

    int NE8 = N * 64 / 8;
    k_init_bf<<<(NE8 + 255) / 256, 256, 0, stream>>>(ego, ego_bf, NE8,
                                                     head_cnt, head_cur, type_cnt, N);
    k_w<<<16, 512, 0, stream>>>(rw, wfrag);

    int nchunks = (E + CHUNK - 1) / CHUNK;
    k1_hist<<<nchunks, 256, 0, stream>>>(head, etyp, E, head_cnt, type_cnt);
    k2a<<<nb2, 512, 0, stream>>>(head_cnt, N, partial);
    k2c<<<nb2, 512, 0, stream>>>(head_cnt, N, partial, head_off, E,
                                 type_cnt, type_off_pad, type_fill, perm_type);
    k3_scatter<<<nchunks, 256, 0, stream>>>(etyp, head, E, head_off, head_cur,
                                            type_fill, perm_type, headpos,
                                            type_off_pad, group_rel);

    int blocks4 = 4096;                    // 16384 waves, ~5 groups each
    int n_waves = blocks4 * (256 / 64);
    k4_scores<<<blocks4, 256, 0, stream>>>(ego_bf, wfrag, head, tail, perm_type,
                                           group_rel, type_off_pad, headpos,
                                           wt_sorted, n_waves);

    k5_agg<<<(N + 3) / 4, 256, 0, stream>>>(ego_bf, wt_sorted, head_off, out, N);
}

// Round 5
// 294.508 us; speedup vs baseline: 1.1813x; 1.1813x over previous
//
#include <hip/hip_runtime.h>
#include <stdint.h>

#define NEG_SLOPE 0.01f
#define CHUNK 4096

typedef float f32x4 __attribute__((ext_vector_type(4)));
typedef short short8 __attribute__((ext_vector_type(8)));

__device__ inline short f2bf(float f) {
    union { float f; uint32_t u; } x; x.f = f;
    uint32_t r = x.u + 0x7FFF + ((x.u >> 16) & 1);   // RNE
    return (short)(r >> 16);
}
__device__ inline float bf2f(unsigned short u) {
    union { uint32_t u; float f; } x; x.u = ((uint32_t)u) << 16; return x.f;
}

// ---------------- K_init_bf: counter init + ego fp32 -> bf16 ----------------
__global__ void __launch_bounds__(256) k_init_bf(
        const float* __restrict__ ego, unsigned short* __restrict__ ego_bf,
        int NE8, int* head_cnt, int* type_cnt, int N) {
    int i = blockIdx.x * 256 + threadIdx.x;
    if (i < N) head_cnt[i] = 0;
    if (i < 16) type_cnt[i] = 0;
    if (i >= NE8) return;
    const float4* p = (const float4*)ego + (size_t)i * 2;
    float4 a = p[0], b = p[1];
    short8 v;
    v[0] = f2bf(a.x); v[1] = f2bf(a.y); v[2] = f2bf(a.z); v[3] = f2bf(a.w);
    v[4] = f2bf(b.x); v[5] = f2bf(b.y); v[6] = f2bf(b.z); v[7] = f2bf(b.w);
    *(short8*)(ego_bf + (size_t)i * 8) = v;
}

// ---------------- K_w: pack W^T as MFMA A-fragments (bf16) ----------------
// A[m = t4*16 + (lane&15)][k = kh*32 + (lane>>4)*8 + j] = W[r][k][m]
__global__ void __launch_bounds__(512) k_w(const float* __restrict__ rw,
                                           short* __restrict__ wfrag) {
    int r = blockIdx.x;
    int tid = threadIdx.x;
    int lane = tid & 63, pair = tid >> 6;
    int t4 = pair >> 1, kh = pair & 1;
    int c = lane & 15, q = lane >> 4;
    int m = t4 * 16 + c;
    short8 f;
    for (int j = 0; j < 8; ++j) {
        int k = kh * 32 + q * 8 + j;
        f[j] = f2bf(rw[r * 4096 + k * 64 + m]);
    }
    *(short8*)(wfrag + ((size_t)((r * 4 + t4) * 2 + kh) * 64 + lane) * 8) = f;
}

// ---------------- K1: histograms; head atomic's return value IS the rank ----
__global__ void __launch_bounds__(256) k1_hist(
        const int* __restrict__ head, const int* __restrict__ etype, int E,
        int* head_cnt, int* type_cnt, int* __restrict__ headrank) {
    __shared__ int lcnt[16];
    int t = threadIdx.x;
    if (t < 16) lcnt[t] = 0;
    __syncthreads();
    long long base = (long long)blockIdx.x * CHUNK;
    for (int i = t; i < CHUNK; i += 256) {
        long long e = base + i;
        if (e < E) {
            headrank[e] = atomicAdd(&head_cnt[head[e]], 1);   // coalesced write
            atomicAdd(&lcnt[etype[e]], 1);
        }
    }
    __syncthreads();
    if (t < 16 && lcnt[t]) atomicAdd(&type_cnt[t], lcnt[t]);
}

// ---------------- K2a: per-block partial sums of head_cnt ----------------
__global__ void __launch_bounds__(512) k2a(const int* __restrict__ head_cnt,
                                           int N, int* partial) {
    __shared__ int sw[8];
    int i = blockIdx.x * 512 + threadIdx.x;
    int v = (i < N) ? head_cnt[i] : 0;
    for (int off = 32; off; off >>= 1) v += __shfl_down(v, off);
    int w = threadIdx.x >> 6, lane = threadIdx.x & 63;
    if (lane == 0) sw[w] = v;
    __syncthreads();
    if (threadIdx.x == 0) {
        int s = 0;
        for (int j = 0; j < 8; ++j) s += sw[j];
        partial[blockIdx.x] = s;
    }
}

// ---------------- K2c: scan -> head_off; block 0 wave 7: type scan + pads ---
__global__ void __launch_bounds__(512) k2c(const int* __restrict__ head_cnt,
                                           int N, const int* __restrict__ partial,
                                           int* head_off, int E,
                                           const int* __restrict__ type_cnt,
                                           int* type_off_pad, int* type_fill,
                                           int4* __restrict__ recs) {
    __shared__ int s[512];
    __shared__ int bo_s;
    int t = threadIdx.x;
    if (t < 64) {
        int acc = 0;
        for (int i = t; i < blockIdx.x; i += 64) acc += partial[i];
        for (int off = 32; off; off >>= 1) acc += __shfl_down(acc, off);
        if (t == 0) bo_s = acc;
    }
    int i = blockIdx.x * 512 + t;
    int v = (i < N) ? head_cnt[i] : 0;
    s[t] = v;
    __syncthreads();
    for (int off = 1; off < 512; off <<= 1) {
        int x = (t >= off) ? s[t - off] : 0;
        __syncthreads();
        s[t] += x;
        __syncthreads();
    }
    if (i < N) head_off[i] = s[t] - v + bo_s;
    if (i == 0) head_off[N] = E;
    // type-bucket scan + pad-record fill (shuffle-only, one wave)
    if (blockIdx.x == 0 && t >= 448) {
        int lane = t & 63;
        int tv = (lane < 16) ? type_cnt[lane] : 0;
        int tp = (tv + 15) & ~15;
        int inc = tp;
        for (int off = 1; off < 16; off <<= 1) {
            int u = __shfl_up(inc, off);
            if (lane >= off) inc += u;
        }
        int excl = inc - tp;
        if (lane < 16) {
            type_off_pad[lane] = excl;
            type_fill[lane] = excl;
            if (lane == 15) type_off_pad[16] = inc;
        }
        for (int r = 0; r < 16; ++r) {
            int b = __shfl(excl, r) + __shfl(tv, r);
            int top1 = (r < 15) ? __shfl(excl, r + 1) : __shfl(inc, 15);
            int pads = top1 - b;
            if (lane < pads) {
                int4 pr; pr.x = 0; pr.y = 0; pr.z = -1; pr.w = r;
                recs[b + lane] = pr;
            }
        }
    }
}

// ---------------- K3: scatter full edge records into type buckets -----------
__global__ void __launch_bounds__(256) k3_scatter(
        const int* __restrict__ etype, const int* __restrict__ head,
        const int* __restrict__ tail, const int* __restrict__ headrank, int E,
        const int* __restrict__ head_off, int* type_fill,
        int4* __restrict__ recs) {
    __shared__ int lcnt[16], lbase[16], lcur[16];
    int t = threadIdx.x;
    if (t < 16) { lcnt[t] = 0; lcur[t] = 0; }
    __syncthreads();
    long long base = (long long)blockIdx.x * CHUNK;
    for (int i = t; i < CHUNK; i += 256) {
        long long e = base + i;
        if (e < E) atomicAdd(&lcnt[etype[e]], 1);
    }
    __syncthreads();
    if (t < 16) lbase[t] = atomicAdd(&type_fill[t], lcnt[t]);
    __syncthreads();
    for (int i = t; i < CHUNK; i += 256) {
        long long e = base + i;
        if (e < E) {
            int ty = etype[e];
            int rk = atomicAdd(&lcur[ty], 1);
            int h = head[e];
            int4 rec;
            rec.x = h;
            rec.y = tail[e];
            rec.z = head_off[h] + headrank[e];   // head_off is L2-resident
            rec.w = ty;
            recs[lbase[ty] + rk] = rec;          // one 16B scatter per edge
        }
    }
}

// ---------------- K4: scores via MFMA; all indices from coalesced records ---
// D = W^T(A-frag) x HeadRows(B-frag): D col (lane&15) = edge slot,
// D row (q*4+i, tiled by t4) = output column. Epilogue: one 8B int2 store
// {exp_bits, tail} at the precomputed head-sorted position.
__global__ void __launch_bounds__(256) k4_scores(
        const unsigned short* __restrict__ ego_bf, const short* __restrict__ wfrag,
        const int4* __restrict__ recs, const int* __restrict__ type_off_pad,
        int2* __restrict__ wt_sorted, int n_waves) {
    int wave = (blockIdx.x * blockDim.x + threadIdx.x) >> 6;
    int lane = threadIdx.x & 63;
    int c = lane & 15, q = lane >> 4;
    int G = type_off_pad[16] >> 4;
    int per = (G + n_waves - 1) / n_waves;
    int g0 = wave * per, g1 = min(G, g0 + per);
    if (g0 >= g1) return;
    const short8 z8 = {0, 0, 0, 0, 0, 0, 0, 0};

    // pipeline: recA = group g (computing), recB = group g+1 (rows in flight)
    int4 recA = recs[(g0 << 4) + c];
    int4 recB;
    if (g0 + 1 < g1) recB = recs[((g0 + 1) << 4) + c];
    else { recB.x = 0; recB.y = 0; recB.z = -1; recB.w = recA.w; }
    // rows for group g0
    const unsigned short* hr = ego_bf + (size_t)recA.x * 64;
    short8 b0c = *(const short8*)(hr + q * 8);
    short8 b1c = *(const short8*)(hr + 32 + q * 8);
    const unsigned short* tr = ego_bf + (size_t)recA.y * 64 + q * 4;
    ushort4 t0c = *(const ushort4*)(tr);
    ushort4 t1c = *(const ushort4*)(tr + 16);
    ushort4 t2c = *(const ushort4*)(tr + 32);
    ushort4 t3c = *(const ushort4*)(tr + 48);

    int cur_r = -1;
    short8 wf[4][2];
    for (int g = g0; g < g1; ++g) {
        // prefetch rows for g+1
        const unsigned short* hrn = ego_bf + (size_t)recB.x * 64;
        short8 b0n = *(const short8*)(hrn + q * 8);
        short8 b1n = *(const short8*)(hrn + 32 + q * 8);
        const unsigned short* trn = ego_bf + (size_t)recB.y * 64 + q * 4;
        ushort4 t0n = *(const ushort4*)(trn);
        ushort4 t1n = *(const ushort4*)(trn + 16);
        ushort4 t2n = *(const ushort4*)(trn + 32);
        ushort4 t3n = *(const ushort4*)(trn + 48);
        // prefetch record for g+2 (coalesced 16B)
        int4 recN;
        if (g + 2 < g1) recN = recs[((g + 2) << 4) + c];
        else { recN.x = 0; recN.y = 0; recN.z = -1; recN.w = recB.w; }
        if (recA.w != cur_r) {                   // wave-uniform, rare
            cur_r = recA.w;
            const short* wp = wfrag + (size_t)cur_r * 4096;
            for (int t4 = 0; t4 < 4; ++t4)
                for (int kh = 0; kh < 2; ++kh)
                    wf[t4][kh] = *(const short8*)(wp + ((t4 * 2 + kh) * 64 + lane) * 8);
        }
        short8 bb0 = b0c, bb1 = b1c;
        if (recA.z < 0) { bb0 = z8; bb1 = z8; }
        f32x4 acc[4];
        for (int t4 = 0; t4 < 4; ++t4) {
            f32x4 a = {0.f, 0.f, 0.f, 0.f};
            a = __builtin_amdgcn_mfma_f32_16x16x32_bf16(wf[t4][0], bb0, a, 0, 0, 0);
            a = __builtin_amdgcn_mfma_f32_16x16x32_bf16(wf[t4][1], bb1, a, 0, 0, 0);
            acc[t4] = a;
        }
        float d = acc[0][0] * bf2f(t0c.x) + acc[0][1] * bf2f(t0c.y)
                + acc[0][2] * bf2f(t0c.z) + acc[0][3] * bf2f(t0c.w)
                + acc[1][0] * bf2f(t1c.x) + acc[1][1] * bf2f(t1c.y)
                + acc[1][2] * bf2f(t1c.z) + acc[1][3] * bf2f(t1c.w)
                + acc[2][0] * bf2f(t2c.x) + acc[2][1] * bf2f(t2c.y)
                + acc[2][2] * bf2f(t2c.z) + acc[2][3] * bf2f(t2c.w)
                + acc[3][0] * bf2f(t3c.x) + acc[3][1] * bf2f(t3c.y)
                + acc[3][2] * bf2f(t3c.z) + acc[3][3] * bf2f(t3c.w);
        d += __shfl_xor(d, 16);
        d += __shfl_xor(d, 32);
        if (q == 0 && recA.z >= 0) {
            float sc = d > 0.f ? d : NEG_SLOPE * d;
            int2 v;
            v.x = __float_as_int(__expf(sc));
            v.y = recA.y;
            wt_sorted[recA.z] = v;               // plain 8B scatter, no atomic
        }
        // rotate pipeline
        recA = recB; recB = recN;
        b0c = b0n; b1c = b1n;
        t0c = t0n; t1c = t1n; t2c = t2n; t3c = t3n;
    }
}

// ---------------- K5: per-head aggregation, batched gathers -----------------
__global__ void __launch_bounds__(256) k5_agg(
        const unsigned short* __restrict__ ego_bf,
        const int2* __restrict__ wt_sorted,
        const int* __restrict__ head_off, float* __restrict__ out, int N) {
    int wave = (blockIdx.x * blockDim.x + threadIdx.x) >> 6;
    int lane = threadIdx.x & 63;
    if (wave >= N) return;
    int g8 = lane >> 3, c8 = lane & 7;   // g8 = edge slot, c8 -> cols 8c8..8c8+7
    int s0 = head_off[wave], s1 = head_off[wave + 1];
    int cnt = s1 - s0;
    float a0 = 0.f, a1 = 0.f, a2 = 0.f, a3 = 0.f;
    float a4 = 0.f, a5 = 0.f, a6 = 0.f, a7 = 0.f, den = 0.f;
    for (int base = s0; base < s1; base += 64) {
        int idx = base + lane;
        int tnL = 0; float wL = 0.f;
        if (idx < s1) {
            int2 p = wt_sorted[idx];             // coalesced
            wL = __int_as_float(p.x);
            tnL = p.y;
        }
        int ng = min(64, s1 - base);
        short8 rows[8];
        float ws[8];
        #pragma unroll
        for (int s = 0; s < 8; ++s) {            // issue all gathers up front
            int j = s * 8 + g8;
            int tn = __shfl(tnL, j);
            ws[s] = __shfl(wL, j);
            if (s * 8 < ng)                       // wave-uniform guard
                rows[s] = *(const short8*)(ego_bf + (size_t)tn * 64 + c8 * 8);
        }
        #pragma unroll
        for (int s = 0; s < 8; ++s) {
            if (s * 8 < ng) {
                float we = ws[s];
                den += we;
                a0 += we * bf2f((unsigned short)rows[s][0]);
                a1 += we * bf2f((unsigned short)rows[s][1]);
                a2 += we * bf2f((unsigned short)rows[s][2]);
                a3 += we * bf2f((unsigned short)rows[s][3]);
                a4 += we * bf2f((unsigned short)rows[s][4]);
                a5 += we * bf2f((unsigned short)rows[s][5]);
                a6 += we * bf2f((unsigned short)rows[s][6]);
                a7 += we * bf2f((unsigned short)rows[s][7]);
            }
        }
    }
    for (int off = 8; off < 64; off <<= 1) {      // sum over g8, keep c8
        den += __shfl_xor(den, off);
        a0 += __shfl_xor(a0, off); a1 += __shfl_xor(a1, off);
        a2 += __shfl_xor(a2, off); a3 += __shfl_xor(a3, off);
        a4 += __shfl_xor(a4, off); a5 += __shfl_xor(a5, off);
        a6 += __shfl_xor(a6, off); a7 += __shfl_xor(a7, off);
    }
    if (lane < 8) {
        float sc = (cnt > 0) ? 1.f / (den * (float)cnt) : 0.f;
        float4 v0 = {a0 * sc, a1 * sc, a2 * sc, a3 * sc};
        float4 v1 = {a4 * sc, a5 * sc, a6 * sc, a7 * sc};
        float* op = out + (size_t)wave * 64 + c8 * 8;
        *(float4*)op = v0;
        *(float4*)(op + 4) = v1;
    }
}

extern "C" void kernel_launch(void* const* d_in, const int* in_sizes, int n_in,
                              void* d_out, int out_size, void* d_ws, size_t ws_size,
                              hipStream_t stream) {
    const float* ego = (const float*)d_in[0];
    const float* rw  = (const float*)d_in[1];
    const int* eidx  = (const int*)d_in[2];
    const int* etyp  = (const int*)d_in[3];
    int N = in_sizes[0] / 64;
    int E = in_sizes[3];
    const int* head = eidx;
    const int* tail = eidx + E;
    float* out = (float*)d_out;

    char* ws = (char*)d_ws;
    size_t o = 0;
    auto take = [&](size_t bytes) -> char* {
        char* p = ws + o;
        o = (o + bytes + 255) & ~(size_t)255;
        return p;
    };
    int PT   = E + 256;
    int nb2  = (N + 511) / 512;
    unsigned short* ego_bf = (unsigned short*)take((size_t)N * 64 * 2);
    short* wfrag      = (short*)take(16 * 4096 * 2);
    int2* wt_sorted   = (int2*)take((size_t)E * 8);
    int4* recs        = (int4*)take((size_t)PT * 16);
    int* headrank     = (int*)take((size_t)E * 4);
    int* head_cnt     = (int*)take((size_t)N * 4);
    int* head_off     = (int*)take((size_t)(N + 1) * 4);
    int* type_cnt     = (int*)take(64);
    int* type_off_pad = (int*)take(68);
    int* type_fill    = (int*)take(64);
    int* partial      = (int*)take((size_t)nb2 * 4);
    (void)ws_size; (void)n_in; (void)out_size;

    int NE8 = N * 64 / 8;
    k_init_bf<<<(NE8 + 255) / 256, 256, 0, stream>>>(ego, ego_bf, NE8,
                                                     head_cnt, type_cnt, N);
    k_w<<<16, 512, 0, stream>>>(rw, wfrag);

    int nchunks = (E + CHUNK - 1) / CHUNK;
    k1_hist<<<nchunks, 256, 0, stream>>>(head, etyp, E, head_cnt, type_cnt, headrank);
    k2a<<<nb2, 512, 0, stream>>>(head_cnt, N, partial);
    k2c<<<nb2, 512, 0, stream>>>(head_cnt, N, partial, head_off, E,
                                 type_cnt, type_off_pad, type_fill, recs);
    k3_scatter<<<nchunks, 256, 0, stream>>>(etyp, head, tail, headrank, E,
                                            head_off, type_fill, recs);

    int blocks4 = 4096;                    // 16384 waves, ~5 groups each
    int n_waves = blocks4 * (256 / 64);
    k4_scores<<<blocks4, 256, 0, stream>>>(ego_bf, wfrag, recs, type_off_pad,
                                           wt_sorted, n_waves);

    k5_agg<<<(N + 3) / 4, 256, 0, stream>>>(ego_bf, wt_sorted, head_off, out, N);
}

// Round 6
// 266.493 us; speedup vs baseline: 1.3055x; 1.1051x over previous
//
#include <hip/hip_runtime.h>
#include <stdint.h>

#define NEG_SLOPE 0.01f
#define CHUNK 4096
#define CHUNK3 2048

typedef float f32x4 __attribute__((ext_vector_type(4)));
typedef short short8 __attribute__((ext_vector_type(8)));

struct RowsT { short8 b0, b1; ushort4 t0, t1, t2, t3; };

__device__ inline short f2bf(float f) {
    union { float f; uint32_t u; } x; x.f = f;
    uint32_t r = x.u + 0x7FFF + ((x.u >> 16) & 1);   // RNE
    return (short)(r >> 16);
}
__device__ inline float bf2f(unsigned short u) {
    union { uint32_t u; float f; } x; x.u = ((uint32_t)u) << 16; return x.f;
}

// ------- K_init_bf: counter init + ego fp32->bf16 + W^T frag pack (merged) --
__global__ void __launch_bounds__(256) k_init_bf(
        const float* __restrict__ ego, unsigned short* __restrict__ ego_bf,
        int NE8, int* head_cnt, int* type_cnt, int N,
        const float* __restrict__ rw, short* __restrict__ wfrag) {
    int i = blockIdx.x * 256 + threadIdx.x;
    if (i < N) head_cnt[i] = 0;
    if (i < 16) type_cnt[i] = 0;
    if (blockIdx.x < 16) {                 // W^T frag pack: blocks 0..15
        int r = blockIdx.x;
        int tid = threadIdx.x;
        int lane = tid & 63;
        int c = lane & 15, q = lane >> 4;
        for (int ph = 0; ph < 2; ++ph) {
            int pair = (tid >> 6) + ph * 4;
            int t4 = pair >> 1, kh = pair & 1;
            int m = t4 * 16 + c;
            short8 f;
            for (int j = 0; j < 8; ++j) {
                int k = kh * 32 + q * 8 + j;
                f[j] = f2bf(rw[r * 4096 + k * 64 + m]);
            }
            *(short8*)(wfrag + ((size_t)((r * 4 + t4) * 2 + kh) * 64 + lane) * 8) = f;
        }
    }
    if (i >= NE8) return;
    const float4* p = (const float4*)ego + (size_t)i * 2;
    float4 a = p[0], b = p[1];
    short8 v;
    v[0] = f2bf(a.x); v[1] = f2bf(a.y); v[2] = f2bf(a.z); v[3] = f2bf(a.w);
    v[4] = f2bf(b.x); v[5] = f2bf(b.y); v[6] = f2bf(b.z); v[7] = f2bf(b.w);
    *(short8*)(ego_bf + (size_t)i * 8) = v;
}

// ---------------- K1: histograms; head atomic's return value IS the rank ----
__global__ void __launch_bounds__(256) k1_hist(
        const int* __restrict__ head, const int* __restrict__ etype, int E,
        int* head_cnt, int* type_cnt, int* __restrict__ headrank) {
    __shared__ int lcnt[16];
    int t = threadIdx.x;
    if (t < 16) lcnt[t] = 0;
    __syncthreads();
    long long base = (long long)blockIdx.x * CHUNK;
    for (int i = t; i < CHUNK; i += 256) {
        long long e = base + i;
        if (e < E) {
            headrank[e] = atomicAdd(&head_cnt[head[e]], 1);   // coalesced write
            atomicAdd(&lcnt[etype[e]], 1);
        }
    }
    __syncthreads();
    if (t < 16 && lcnt[t]) atomicAdd(&type_cnt[t], lcnt[t]);
}

// ---------------- K2a: per-block partial sums of head_cnt ----------------
__global__ void __launch_bounds__(512) k2a(const int* __restrict__ head_cnt,
                                           int N, int* partial) {
    __shared__ int sw[8];
    int i = blockIdx.x * 512 + threadIdx.x;
    int v = (i < N) ? head_cnt[i] : 0;
    for (int off = 32; off; off >>= 1) v += __shfl_down(v, off);
    int w = threadIdx.x >> 6, lane = threadIdx.x & 63;
    if (lane == 0) sw[w] = v;
    __syncthreads();
    if (threadIdx.x == 0) {
        int s = 0;
        for (int j = 0; j < 8; ++j) s += sw[j];
        partial[blockIdx.x] = s;
    }
}

// ---------------- K2c: scan -> head_off; block 0 wave 7: type scan + pads ---
__global__ void __launch_bounds__(512) k2c(const int* __restrict__ head_cnt,
                                           int N, const int* __restrict__ partial,
                                           int* head_off, int E,
                                           const int* __restrict__ type_cnt,
                                           int* type_off_pad, int* type_fill,
                                           int4* __restrict__ recs) {
    __shared__ int s[512];
    __shared__ int bo_s;
    int t = threadIdx.x;
    if (t < 64) {
        int acc = 0;
        for (int i = t; i < blockIdx.x; i += 64) acc += partial[i];
        for (int off = 32; off; off >>= 1) acc += __shfl_down(acc, off);
        if (t == 0) bo_s = acc;
    }
    int i = blockIdx.x * 512 + t;
    int v = (i < N) ? head_cnt[i] : 0;
    s[t] = v;
    __syncthreads();
    for (int off = 1; off < 512; off <<= 1) {
        int x = (t >= off) ? s[t - off] : 0;
        __syncthreads();
        s[t] += x;
        __syncthreads();
    }
    if (i < N) head_off[i] = s[t] - v + bo_s;
    if (i == 0) head_off[N] = E;
    // type-bucket scan + pad-record fill (shuffle-only, one wave)
    if (blockIdx.x == 0 && t >= 448) {
        int lane = t & 63;
        int tv = (lane < 16) ? type_cnt[lane] : 0;
        int tp = (tv + 15) & ~15;
        int inc = tp;
        for (int off = 1; off < 16; off <<= 1) {
            int u = __shfl_up(inc, off);
            if (lane >= off) inc += u;
        }
        int excl = inc - tp;
        if (lane < 16) {
            type_off_pad[lane] = excl;
            type_fill[lane] = excl;
            if (lane == 15) type_off_pad[16] = inc;
        }
        for (int r = 0; r < 16; ++r) {
            int b = __shfl(excl, r) + __shfl(tv, r);
            int top1 = (r < 15) ? __shfl(excl, r + 1) : __shfl(inc, 15);
            int pads = top1 - b;
            if (lane < pads) {
                int4 pr; pr.x = 0; pr.y = 0; pr.z = -1; pr.w = r;
                recs[b + lane] = pr;
            }
        }
    }
}

// ------- K3: LDS-staged type scatter -> coalesced full-line record writes ---
__global__ void __launch_bounds__(256) k3_scatter(
        const int* __restrict__ etype, const int* __restrict__ head,
        const int* __restrict__ tail, const int* __restrict__ headrank, int E,
        const int* __restrict__ head_off, int* type_fill,
        int4* __restrict__ recs) {
    __shared__ int lcnt[16], lbase[16], loff[16];
    __shared__ int4 lrec[CHUNK3];
    int t = threadIdx.x;
    if (t < 16) lcnt[t] = 0;
    __syncthreads();
    long long base = (long long)blockIdx.x * CHUNK3;
    int myty[8], myrk[8];
    #pragma unroll
    for (int sIt = 0; sIt < 8; ++sIt) {
        long long e = base + t + sIt * 256;
        int ty = -1, rk = 0;
        if (e < E) { ty = etype[e]; rk = atomicAdd(&lcnt[ty], 1); }
        myty[sIt] = ty; myrk[sIt] = rk;
    }
    __syncthreads();
    if (t < 16) lbase[t] = atomicAdd(&type_fill[t], lcnt[t]);
    if (t >= 64 && t < 128) {              // one wave: exclusive scan of lcnt
        int lane = t - 64;
        int v = (lane < 16) ? lcnt[lane] : 0;
        int inc = v;
        for (int off = 1; off < 16; off <<= 1) {
            int u = __shfl_up(inc, off);
            if (lane >= off) inc += u;
        }
        if (lane < 16) loff[lane] = inc - v;
    }
    __syncthreads();
    #pragma unroll
    for (int sIt = 0; sIt < 8; ++sIt) {
        long long e = base + t + sIt * 256;
        if (e < E) {
            int h = head[e];
            int4 rec;
            rec.x = h;
            rec.y = tail[e];
            rec.z = head_off[h] + headrank[e];
            rec.w = myty[sIt];
            lrec[loff[myty[sIt]] + myrk[sIt]] = rec;
        }
    }
    __syncthreads();
    int nvalid = (int)(((long long)E - base < CHUNK3) ? ((long long)E - base) : CHUNK3);
    for (int i = t; i < nvalid; i += 256) {
        int4 rec = lrec[i];
        int r = rec.w;
        recs[lbase[r] + (i - loff[r])] = rec;    // coalesced by-type segments
    }
}

// ---------------- K4: scores via MFMA, DUAL-stream pipelined ----------------
// D = W^T(A-frag) x HeadRows(B-frag): D col (lane&15) = edge slot,
// D row (q*4+i, tiled by t4) = output column. Two independent group
// pipelines per wave double the load issue-to-consume distance.
__global__ void __launch_bounds__(256) k4_scores(
        const unsigned short* __restrict__ ego_bf, const short* __restrict__ wfrag,
        const int4* __restrict__ recs, const int* __restrict__ type_off_pad,
        int2* __restrict__ wt_sorted, int n_waves) {
    int wave = (blockIdx.x * blockDim.x + threadIdx.x) >> 6;
    int lane = threadIdx.x & 63;
    int c = lane & 15, q = lane >> 4;
    int G = type_off_pad[16] >> 4;
    int per = (G + n_waves - 1) / n_waves;
    int g0 = wave * per, g1 = min(G, g0 + per);
    if (g0 >= g1) return;

    int cur_r = -1;
    short8 wf[4][2];

    auto loadrec = [&](int g, int wdef) -> int4 {
        if (g < g1) return recs[((size_t)g << 4) + c];
        int4 p; p.x = 0; p.y = 0; p.z = -1; p.w = wdef;
        return p;
    };
    auto loadrows = [&](const int4& rec, RowsT& r) {
        const unsigned short* hr = ego_bf + (size_t)rec.x * 64;
        r.b0 = *(const short8*)(hr + q * 8);
        r.b1 = *(const short8*)(hr + 32 + q * 8);
        const unsigned short* tr = ego_bf + (size_t)rec.y * 64 + q * 4;
        r.t0 = *(const ushort4*)(tr);
        r.t1 = *(const ushort4*)(tr + 16);
        r.t2 = *(const ushort4*)(tr + 32);
        r.t3 = *(const ushort4*)(tr + 48);
    };
    auto compute = [&](const int4& rec, const RowsT& rw) {
        if (rec.w != cur_r) {                    // wave-uniform, rare
            cur_r = rec.w;
            const short* wp = wfrag + (size_t)cur_r * 4096;
            for (int t4 = 0; t4 < 4; ++t4)
                for (int kh = 0; kh < 2; ++kh)
                    wf[t4][kh] = *(const short8*)(wp + ((t4 * 2 + kh) * 64 + lane) * 8);
        }
        f32x4 acc[4];
        for (int t4 = 0; t4 < 4; ++t4) {
            f32x4 a = {0.f, 0.f, 0.f, 0.f};
            a = __builtin_amdgcn_mfma_f32_16x16x32_bf16(wf[t4][0], rw.b0, a, 0, 0, 0);
            a = __builtin_amdgcn_mfma_f32_16x16x32_bf16(wf[t4][1], rw.b1, a, 0, 0, 0);
            acc[t4] = a;
        }
        float d = acc[0][0] * bf2f(rw.t0.x) + acc[0][1] * bf2f(rw.t0.y)
                + acc[0][2] * bf2f(rw.t0.z) + acc[0][3] * bf2f(rw.t0.w)
                + acc[1][0] * bf2f(rw.t1.x) + acc[1][1] * bf2f(rw.t1.y)
                + acc[1][2] * bf2f(rw.t1.z) + acc[1][3] * bf2f(rw.t1.w)
                + acc[2][0] * bf2f(rw.t2.x) + acc[2][1] * bf2f(rw.t2.y)
                + acc[2][2] * bf2f(rw.t2.z) + acc[2][3] * bf2f(rw.t2.w)
                + acc[3][0] * bf2f(rw.t3.x) + acc[3][1] * bf2f(rw.t3.y)
                + acc[3][2] * bf2f(rw.t3.z) + acc[3][3] * bf2f(rw.t3.w);
        d += __shfl_xor(d, 16);
        d += __shfl_xor(d, 32);
        if (q == 0 && rec.z >= 0) {
            float s = d > 0.f ? d : NEG_SLOPE * d;
            int2 v;
            v.x = __float_as_int(__expf(s));
            v.y = rec.y;
            wt_sorted[rec.z] = v;                // plain 8B scatter, no atomic
        }
    };

    int gA = g0, gB = g0 + 1;
    int4 recA  = loadrec(gA, 0);
    int4 recB  = loadrec(gB, recA.w);
    int4 recA1 = loadrec(gA + 2, recA.w);
    int4 recB1 = loadrec(gB + 2, recB.w);
    RowsT rowsA, rowsB;
    loadrows(recA, rowsA);
    loadrows(recB, rowsB);
    while (gA < g1) {
        int4 recA2 = loadrec(gA + 4, recA1.w);
        int4 recB2 = loadrec(gB + 4, recB1.w);
        compute(recA, rowsA);
        RowsT rowsA1; loadrows(recA1, rowsA1);   // in flight across B-compute
        compute(recB, rowsB);
        RowsT rowsB1; loadrows(recB1, rowsB1);   // in flight across next A
        recA = recA1; recA1 = recA2; rowsA = rowsA1;
        recB = recB1; recB1 = recB2; rowsB = rowsB1;
        gA += 2; gB += 2;
    }
}

// ---------------- K5: aggregation, one 16-lane quarter per head -------------
__global__ void __launch_bounds__(256) k5_agg(
        const unsigned short* __restrict__ ego_bf,
        const int2* __restrict__ wt_sorted,
        const int* __restrict__ head_off, float* __restrict__ out, int N) {
    int wave = (blockIdx.x * blockDim.x + threadIdx.x) >> 6;
    int lane = threadIdx.x & 63;
    int quarter = lane >> 4, lq = lane & 15;
    int g2 = lq >> 3, c8 = lq & 7;       // 2 edge slots x 8 col-lanes per quarter
    int h = wave * 4 + quarter;
    if (wave * 4 >= N) return;
    bool hv = h < N;
    int s0 = hv ? head_off[h] : 0;
    int s1 = hv ? head_off[h + 1] : 0;
    int cnt = s1 - s0;
    float acc[8] = {0.f, 0.f, 0.f, 0.f, 0.f, 0.f, 0.f, 0.f};
    float den = 0.f;
    int qb = quarter << 4;
    for (int base = s0; base < s1; base += 16) {
        int idx = base + lq;
        int tnL = 0; float wL = 0.f;
        if (idx < s1) {
            int2 p = wt_sorted[idx];             // ~contiguous across quarters
            wL = __int_as_float(p.x);
            tnL = p.y;
        }
        int ng = min(16, s1 - base);
        short8 rows[8]; float ws[8];
        #pragma unroll
        for (int sIt = 0; sIt < 8; ++sIt) {      // issue all gathers up front
            int j = sIt * 2 + g2;
            int tn = __shfl(tnL, qb + j);
            ws[sIt] = __shfl(wL, qb + j);
            if (sIt * 2 < ng)
                rows[sIt] = *(const short8*)(ego_bf + (size_t)tn * 64 + c8 * 8);
        }
        #pragma unroll
        for (int sIt = 0; sIt < 8; ++sIt) {
            if (sIt * 2 < ng) {
                float we = ws[sIt];
                den += we;
                #pragma unroll
                for (int k = 0; k < 8; ++k)
                    acc[k] += we * bf2f((unsigned short)rows[sIt][k]);
            }
        }
    }
    den += __shfl_xor(den, 8);                   // reduce over the 2 edge slots
    #pragma unroll
    for (int k = 0; k < 8; ++k) acc[k] += __shfl_xor(acc[k], 8);
    if (hv && g2 == 0) {
        float sc = (cnt > 0) ? 1.f / (den * (float)cnt) : 0.f;
        float4 v0 = {acc[0] * sc, acc[1] * sc, acc[2] * sc, acc[3] * sc};
        float4 v1 = {acc[4] * sc, acc[5] * sc, acc[6] * sc, acc[7] * sc};
        float* op = out + (size_t)h * 64 + c8 * 8;
        *(float4*)op = v0;
        *(float4*)(op + 4) = v1;
    }
}

extern "C" void kernel_launch(void* const* d_in, const int* in_sizes, int n_in,
                              void* d_out, int out_size, void* d_ws, size_t ws_size,
                              hipStream_t stream) {
    const float* ego = (const float*)d_in[0];
    const float* rw  = (const float*)d_in[1];
    const int* eidx  = (const int*)d_in[2];
    const int* etyp  = (const int*)d_in[3];
    int N = in_sizes[0] / 64;
    int E = in_sizes[3];
    const int* head = eidx;
    const int* tail = eidx + E;
    float* out = (float*)d_out;

    char* ws = (char*)d_ws;
    size_t o = 0;
    auto take = [&](size_t bytes) -> char* {
        char* p = ws + o;
        o = (o + bytes + 255) & ~(size_t)255;
        return p;
    };
    int PT  = E + 256;
    int nb2 = (N + 511) / 512;
    unsigned short* ego_bf = (unsigned short*)take((size_t)N * 64 * 2);
    short* wfrag      = (short*)take(16 * 4096 * 2);
    int2* wt_sorted   = (int2*)take((size_t)E * 8);
    int4* recs        = (int4*)take((size_t)PT * 16);
    int* headrank     = (int*)take((size_t)E * 4);
    int* head_cnt     = (int*)take((size_t)N * 4);
    int* head_off     = (int*)take((size_t)(N + 1) * 4);
    int* type_cnt     = (int*)take(64);
    int* type_off_pad = (int*)take(68);
    int* type_fill    = (int*)take(64);
    int* partial      = (int*)take((size_t)nb2 * 4);
    (void)ws_size; (void)n_in; (void)out_size;

    int NE8 = N * 64 / 8;
    k_init_bf<<<(NE8 + 255) / 256, 256, 0, stream>>>(ego, ego_bf, NE8,
                                                     head_cnt, type_cnt, N,
                                                     rw, wfrag);
    int nchunks = (E + CHUNK - 1) / CHUNK;
    k1_hist<<<nchunks, 256, 0, stream>>>(head, etyp, E, head_cnt, type_cnt, headrank);
    k2a<<<nb2, 512, 0, stream>>>(head_cnt, N, partial);
    k2c<<<nb2, 512, 0, stream>>>(head_cnt, N, partial, head_off, E,
                                 type_cnt, type_off_pad, type_fill, recs);
    int nchunks3 = (E + CHUNK3 - 1) / CHUNK3;
    k3_scatter<<<nchunks3, 256, 0, stream>>>(etyp, head, tail, headrank, E,
                                             head_off, type_fill, recs);

    int blocks4 = 2048;                    // 8192 waves, ~10 groups = ~5 pairs
    int n_waves = blocks4 * (256 / 64);
    k4_scores<<<blocks4, 256, 0, stream>>>(ego_bf, wfrag, recs, type_off_pad,
                                           wt_sorted, n_waves);

    k5_agg<<<(N + 15) / 16, 256, 0, stream>>>(ego_bf, wt_sorted, head_off, out, N);
}